// Round 2
// baseline (163.712 us; speedup 1.0000x reference)
//
#include <hip/hip_runtime.h>
#include <hip/hip_bf16.h>

#define EPSF 1e-6f

// 32-lane butterfly reduction (xor masks <32 stay within each 32-lane half of a wave64)
__device__ __forceinline__ float red32(float v) {
    v += __shfl_xor(v, 16);
    v += __shfl_xor(v, 8);
    v += __shfl_xor(v, 4);
    v += __shfl_xor(v, 2);
    v += __shfl_xor(v, 1);
    return v;
}

__device__ __forceinline__ float sigm(float x) {
    return 1.0f / (1.0f + expf(-x));
}

// ---------------------------------------------------------------------------
// Phase 1: per-node precompute.
// Computes y (hyperboloid point after linear+bias), and per-node projections:
//   A_i    = u_i @ att_w1[0:32,:]  + att_b1    (ul part of att_in)
//   B_j    = u_j @ att_w1[32:64,:]             (ur part of att_in)
//   base_j = u_j @ msg_w1[0:32,:]  + msg_b1    (ur part of msg_in)
// One wave per node; lane k (mod 32) holds component k. Lanes 32-63 duplicate.
// ---------------------------------------------------------------------------
__global__ __launch_bounds__(256) void hgcn_phase1(
    const float* __restrict__ x, const float* __restrict__ W_lin,
    const float* __restrict__ b_lin, const float* __restrict__ att_w1,
    const float* __restrict__ att_b1, const float* __restrict__ msg_w1,
    const float* __restrict__ msg_b1,
    float* __restrict__ yv, float* __restrict__ Av,
    float* __restrict__ Bv, float* __restrict__ basev, int n_nodes)
{
    int wave = threadIdx.x >> 6;
    int node = blockIdx.x * 4 + wave;
    if (node >= n_nodes) return;
    int lane = threadIdx.x & 63;
    int k = lane & 31;

    float xk = x[node * 32 + k];
    // u = logmap0(x)
    float x0 = __shfl(xk, 0, 32);
    float dd = acoshf(fmaxf(x0, 1.0f + EPSF));
    float sp = sqrtf(fmaxf(x0 * x0 - 1.0f, EPSF));
    float u = (k == 0) ? 0.0f : (dd / sp) * xk;

    // h = proj_tan0(u @ W_lin)
    float h = 0.0f;
    #pragma unroll 8
    for (int d0 = 0; d0 < 32; ++d0) {
        float ud = __shfl(u, d0, 32);
        h = fmaf(ud, W_lin[d0 * 32 + k], h);
    }
    if (k == 0) h = 0.0f;

    // y = expmap0(h)
    float nn = red32(h * h);
    float n = sqrtf(fmaxf(nn, EPSF));
    float y = (k == 0) ? coshf(n) : (sinhf(n) / n) * h;

    // bias = transp0(y, proj_tan0(b_lin))
    float pb = (k == 0) ? 0.0f : b_lin[k];
    float y0 = __shfl(y, 0, 32);
    float lin = red32((k == 0) ? 0.0f : y * pb);
    float coef = lin / (1.0f + y0);
    float bias = pb + coef * ((k == 0) ? (y0 + 1.0f) : y);

    // y = expmap(y, bias)
    float li = red32((k == 0) ? -bias * bias : bias * bias);
    float un = sqrtf(fmaxf(li, EPSF));
    float y2 = coshf(un) * y + (sinhf(un) / un) * bias;

    // u2 = logmap0(y)
    float y20 = __shfl(y2, 0, 32);
    float dd2 = acoshf(fmaxf(y20, 1.0f + EPSF));
    float sp2 = sqrtf(fmaxf(y20 * y20 - 1.0f, EPSF));
    float u2 = (k == 0) ? 0.0f : (dd2 / sp2) * y2;

    // per-node projections
    float A = att_b1[k];
    float B = 0.0f;
    float bs = msg_b1[k];
    #pragma unroll 8
    for (int d0 = 0; d0 < 32; ++d0) {
        float ud = __shfl(u2, d0, 32);
        A = fmaf(ud, att_w1[d0 * 32 + k], A);
        B = fmaf(ud, att_w1[(32 + d0) * 32 + k], B);
        bs = fmaf(ud, msg_w1[d0 * 32 + k], bs);
    }

    if (lane < 32) {
        yv[node * 32 + k] = y2;
        Av[node * 32 + k] = A;
        Bv[node * 32 + k] = B;
        basev[node * 32 + k] = bs;
    }
}

// ---------------------------------------------------------------------------
// Phase 2: one wave per output row (b,i). Scans adj row in 64-wide chunks,
// ballots active edges, processes 2 active edges/iter (one per 32-lane half,
// lane = feature dim). Accumulates sum_j att*relu(msg_hidden) and sum_j att,
// then applies msg_w2 outside the sum (linearity), out-MLP, and the full
// hyperbolic epilogue + layernorm. Writes 32 output floats per row.
// ---------------------------------------------------------------------------
__global__ __launch_bounds__(256) void hgcn_phase2(
    const float* __restrict__ adj,
    const float* __restrict__ yv, const float* __restrict__ Av,
    const float* __restrict__ Bv, const float* __restrict__ basev,
    const float* __restrict__ att_w1, const float* __restrict__ att_w2,
    const float* __restrict__ att_b2, const float* __restrict__ msg_w1,
    const float* __restrict__ msg_w2, const float* __restrict__ msg_b2,
    const float* __restrict__ out_w1, const float* __restrict__ out_b1,
    const float* __restrict__ out_w2, const float* __restrict__ out_b2,
    const float* __restrict__ ln_g, const float* __restrict__ ln_b,
    float* __restrict__ out, int Bn, int N)
{
    int wave = threadIdx.x >> 6;
    int row = blockIdx.x * 4 + wave;          // row = b*N + i
    if (row >= Bn) return;
    int b = row / N;
    int lane = threadIdx.x & 63;
    int half = lane >> 5;
    int k = lane & 31;

    float yi = yv[row * 32 + k];
    float Ai = Av[row * 32 + k];
    float yi0 = __shfl(yi, 0, 32);
    float w64 = att_w1[64 * 32 + k];          // adj coefficient row
    float w65 = att_w1[65 * 32 + k];          // edge_attr coefficient row
    float aw2 = att_w2[k];
    float ab2 = att_b2[0];
    float mw32 = msg_w1[32 * 32 + k];         // edge_attr row of msg_w1

    const float* adjrow = adj + (size_t)row * N;
    const float* ybase = yv + (size_t)b * N * 32;
    const float* Bbase = Bv + (size_t)b * N * 32;
    const float* bbase = basev + (size_t)b * N * 32;

    float macc = 0.0f;     // sum_j att * relu(msg hidden)   (lane k = dim k)
    float attsum = 0.0f;   // sum_j att

    for (int jb = 0; jb < N; jb += 64) {
        float aval = (jb + lane < N) ? adjrow[jb + lane] : 0.0f;
        unsigned long long mask = __ballot(aval != 0.0f);
        while (mask) {
            int j0 = __ffsll((unsigned long long)mask) - 1; mask &= mask - 1;
            int j1 = -1;
            if (mask) { j1 = __ffsll((unsigned long long)mask) - 1; mask &= mask - 1; }
            int myj = half ? j1 : j0;
            if (myj >= 0) {
                int j = jb + myj;
                float a = __shfl(aval, myj, 64);
                float yj = ybase[(size_t)j * 32 + k];
                float Bj = Bbase[(size_t)j * 32 + k];
                float bj = bbase[(size_t)j * 32 + k];
                // edge_attr = arccosh(max(-l_inner(y_i, y_j), 1+eps))
                float v = (k == 0) ? yi * yj : -yi * yj;
                float z = red32(v);
                z = fmaxf(z, 1.0f + EPSF);
                float e = acoshf(z);
                // att hidden -> silu -> att_w2 dot -> sigmoid
                float hA = Ai + Bj + a * w64 + e * w65;
                float sl = hA * sigm(hA);     // silu
                float s = red32(sl * aw2) + ab2;
                float att = sigm(s) * a;
                // msg hidden -> relu, weighted accumulate
                float m = fmaf(e, mw32, bj);
                macc = fmaf(att, fmaxf(m, 0.0f), macc);
                attsum += att;
            }
        }
    }

    // combine the two halves
    macc += __shfl_xor(macc, 32);
    attsum += __shfl_xor(attsum, 32);

    // msg = macc @ msg_w2 + attsum * msg_b2   (linearity of W2 over the j-sum)
    float msg = attsum * msg_b2[k];
    #pragma unroll 8
    for (int d0 = 0; d0 < 32; ++d0) {
        float v = __shfl(macc, d0, 32);
        msg = fmaf(v, msg_w2[d0 * 32 + k], msg);
    }

    // out MLP: relu(msg @ out_w1 + b1) @ out_w2 + b2
    float t = out_b1[k];
    #pragma unroll 8
    for (int d0 = 0; d0 < 32; ++d0) {
        float v = __shfl(msg, d0, 32);
        t = fmaf(v, out_w1[d0 * 32 + k], t);
    }
    t = fmaxf(t, 0.0f);
    float m2 = out_b2[k];
    #pragma unroll 8
    for (int d0 = 0; d0 < 32; ++d0) {
        float v = __shfl(t, d0, 32);
        m2 = fmaf(v, out_w2[d0 * 32 + k], m2);
    }

    // msg3 = transp0(y, proj_tan0(m2))
    float pm = (k == 0) ? 0.0f : m2;
    float lin = red32((k == 0) ? 0.0f : yi * pm);
    float coef = lin / (1.0f + yi0);
    float msg3 = pm + coef * ((k == 0) ? (yi0 + 1.0f) : yi);

    // h2 = expmap(y, msg3)
    float li = red32((k == 0) ? -msg3 * msg3 : msg3 * msg3);
    float un = sqrtf(fmaxf(li, EPSF));
    float h2 = coshf(un) * yi + (sinhf(un) / un) * msg3;

    // u2 = logmap0(h2)
    float h20 = __shfl(h2, 0, 32);
    float dd = acoshf(fmaxf(h20, 1.0f + EPSF));
    float sp = sqrtf(fmaxf(h20 * h20 - 1.0f, EPSF));
    float u2 = (k == 0) ? 0.0f : (dd / sp) * h2;

    // layernorm over components 1..31
    float mu = red32(u2) * (1.0f / 31.0f);            // u2[k=0] is 0
    float dv = (k == 0) ? 0.0f : (u2 - mu);
    float var = red32(dv * dv) * (1.0f / 31.0f);
    float inv = 1.0f / sqrtf(var + 1e-5f);
    float spk = (k == 0) ? 0.0f : fmaf(dv * inv, ln_g[k - 1], ln_b[k - 1]);

    // h2 = expmap0([u2_0, sp])   (u2_0 ignored by expmap0)
    float nn2 = red32(spk * spk);
    float n2 = sqrtf(fmaxf(nn2, EPSF));
    float h2b = (k == 0) ? coshf(n2) : (sinhf(n2) / n2) * spk;

    // out = expmap0(proj_tan0(relu(logmap0(h2))))
    float hb0 = __shfl(h2b, 0, 32);
    float ddb = acoshf(fmaxf(hb0, 1.0f + EPSF));
    float spb = sqrtf(fmaxf(hb0 * hb0 - 1.0f, EPSF));
    float r = (k == 0) ? 0.0f : fmaxf((ddb / spb) * h2b, 0.0f);
    float nn3 = red32(r * r);
    float n3 = sqrtf(fmaxf(nn3, EPSF));
    float o = (k == 0) ? coshf(n3) : (sinhf(n3) / n3) * r;

    if (lane < 32) out[row * 32 + k] = o;
}

extern "C" void kernel_launch(void* const* d_in, const int* in_sizes, int n_in,
                              void* d_out, int out_size, void* d_ws, size_t ws_size,
                              hipStream_t stream) {
    const float* x      = (const float*)d_in[0];
    const float* adj    = (const float*)d_in[1];
    const float* W_lin  = (const float*)d_in[2];
    const float* b_lin  = (const float*)d_in[3];
    const float* att_w1 = (const float*)d_in[4];
    const float* att_b1 = (const float*)d_in[5];
    const float* att_w2 = (const float*)d_in[6];
    const float* att_b2 = (const float*)d_in[7];
    const float* msg_w1 = (const float*)d_in[8];
    const float* msg_b1 = (const float*)d_in[9];
    const float* msg_w2 = (const float*)d_in[10];
    const float* msg_b2 = (const float*)d_in[11];
    const float* out_w1 = (const float*)d_in[12];
    const float* out_b1 = (const float*)d_in[13];
    const float* out_w2 = (const float*)d_in[14];
    const float* out_b2 = (const float*)d_in[15];
    const float* ln_g   = (const float*)d_in[16];
    const float* ln_b   = (const float*)d_in[17];

    float* out = (float*)d_out;

    const int D = 32;
    const int BN = in_sizes[0] / D;      // b*n = 1536
    const int N = in_sizes[1] / BN;      // 768
    // b = BN / N = 2

    float* yv    = (float*)d_ws;
    float* Av    = yv + (size_t)BN * D;
    float* Bv    = Av + (size_t)BN * D;
    float* basev = Bv + (size_t)BN * D;

    int blocks = (BN + 3) / 4;
    hipLaunchKernelGGL(hgcn_phase1, dim3(blocks), dim3(256), 0, stream,
                       x, W_lin, b_lin, att_w1, att_b1, msg_w1, msg_b1,
                       yv, Av, Bv, basev, BN);
    hipLaunchKernelGGL(hgcn_phase2, dim3(blocks), dim3(256), 0, stream,
                       adj, yv, Av, Bv, basev,
                       att_w1, att_w2, att_b2, msg_w1, msg_w2, msg_b2,
                       out_w1, out_b1, out_w2, out_b2, ln_g, ln_b,
                       out, BN, N);
    // pass-through second output: adj
    hipMemcpyAsync(out + (size_t)BN * D, adj, (size_t)in_sizes[1] * sizeof(float),
                   hipMemcpyDeviceToDevice, stream);
}

// Round 12
// 118.609 us; speedup vs baseline: 1.3803x; 1.3803x over previous
//
#include <hip/hip_runtime.h>
#include <hip/hip_bf16.h>

#define EPSF 1e-6f

// 32-lane butterfly reduction (xor masks <32 stay within each 32-lane half of a wave64)
__device__ __forceinline__ float red32(float v) {
    v += __shfl_xor(v, 16);
    v += __shfl_xor(v, 8);
    v += __shfl_xor(v, 4);
    v += __shfl_xor(v, 2);
    v += __shfl_xor(v, 1);
    return v;
}

// fast native transcendentals (v_exp_f32 / v_log_f32 / v_rcp_f32)
__device__ __forceinline__ float frcp(float x) { return __builtin_amdgcn_rcpf(x); }
__device__ __forceinline__ float fsigm(float x) { return frcp(1.0f + __expf(-x)); }
// valid for z >= 1+eps (our callers clamp first)
__device__ __forceinline__ float facosh(float z) {
    return __logf(z + sqrtf(fmaxf(z * z - 1.0f, 0.0f)));
}
__device__ __forceinline__ float2 fsinhcosh(float x) {
    float e = __expf(x);
    float ei = frcp(e);
    return make_float2(0.5f * (e - ei), 0.5f * (e + ei));  // (sinh, cosh)
}

// ---------------------------------------------------------------------------
// Phase 1: per-node precompute. One wave per node; lane k (mod 32) = dim k.
//   yv     = hyperboloid point after linear+bias chain
//   Av     = u @ att_w1[0:32,:]  + att_b1
//   Bv     = u @ att_w1[32:64,:]
//   basev  = u @ msg_w1[0:32,:]  + msg_b1
// ---------------------------------------------------------------------------
__global__ __launch_bounds__(256) void hgcn_phase1(
    const float* __restrict__ x, const float* __restrict__ W_lin,
    const float* __restrict__ b_lin, const float* __restrict__ att_w1,
    const float* __restrict__ att_b1, const float* __restrict__ msg_w1,
    const float* __restrict__ msg_b1,
    float* __restrict__ yv, float* __restrict__ Av,
    float* __restrict__ Bv, float* __restrict__ basev, int n_nodes)
{
    int wave = threadIdx.x >> 6;
    int node = blockIdx.x * 4 + wave;
    if (node >= n_nodes) return;
    int lane = threadIdx.x & 63;
    int k = lane & 31;

    float xk = x[node * 32 + k];
    // u = logmap0(x)
    float x0 = __shfl(xk, 0, 32);
    float dd = facosh(fmaxf(x0, 1.0f + EPSF));
    float sp = sqrtf(fmaxf(x0 * x0 - 1.0f, EPSF));
    float u = (k == 0) ? 0.0f : (dd / sp) * xk;

    // h = proj_tan0(u @ W_lin)
    float h = 0.0f;
    #pragma unroll 8
    for (int d0 = 0; d0 < 32; ++d0) {
        float ud = __shfl(u, d0, 32);
        h = fmaf(ud, W_lin[d0 * 32 + k], h);
    }
    if (k == 0) h = 0.0f;

    // y = expmap0(h)
    float nn = red32(h * h);
    float n = sqrtf(fmaxf(nn, EPSF));
    float2 sc = fsinhcosh(n);
    float y = (k == 0) ? sc.y : (sc.x / n) * h;

    // bias = transp0(y, proj_tan0(b_lin))
    float pb = (k == 0) ? 0.0f : b_lin[k];
    float y0 = __shfl(y, 0, 32);
    float lin = red32((k == 0) ? 0.0f : y * pb);
    float coef = lin / (1.0f + y0);
    float bias = pb + coef * ((k == 0) ? (y0 + 1.0f) : y);

    // y = expmap(y, bias)
    float li = red32((k == 0) ? -bias * bias : bias * bias);
    float un = sqrtf(fmaxf(li, EPSF));
    float2 sc2 = fsinhcosh(un);
    float y2 = sc2.y * y + (sc2.x / un) * bias;

    // u2 = logmap0(y)
    float y20 = __shfl(y2, 0, 32);
    float dd2 = facosh(fmaxf(y20, 1.0f + EPSF));
    float sp2 = sqrtf(fmaxf(y20 * y20 - 1.0f, EPSF));
    float u2 = (k == 0) ? 0.0f : (dd2 / sp2) * y2;

    // per-node projections
    float A = att_b1[k];
    float B = 0.0f;
    float bs = msg_b1[k];
    #pragma unroll 8
    for (int d0 = 0; d0 < 32; ++d0) {
        float ud = __shfl(u2, d0, 32);
        A = fmaf(ud, att_w1[d0 * 32 + k], A);
        B = fmaf(ud, att_w1[(32 + d0) * 32 + k], B);
        bs = fmaf(ud, msg_w1[d0 * 32 + k], bs);
    }

    if (lane < 32) {
        yv[node * 32 + k] = y2;
        Av[node * 32 + k] = A;
        Bv[node * 32 + k] = B;
        basev[node * 32 + k] = bs;
    }
}

// ---------------------------------------------------------------------------
// Phase 2: one BLOCK per output row (4 waves split the 768-column adj scan,
// 192 columns each). Each wave ballots its chunks and processes 2 active
// edges/iter (one per 32-lane half, lane = feature dim). Partial sums are
// combined through LDS; wave 0 runs the epilogue (msg_w2 via linearity,
// out-MLP, transp0/expmap/logmap chain, layernorm, final expmaps).
// Blocks with blockIdx.x >= Bn instead copy adj -> out (second tuple output),
// replacing the slow graph-captured SDMA memcpy.
// ---------------------------------------------------------------------------
__global__ __launch_bounds__(256) void hgcn_phase2(
    const float* __restrict__ adj,
    const float* __restrict__ yv, const float* __restrict__ Av,
    const float* __restrict__ Bv, const float* __restrict__ basev,
    const float* __restrict__ att_w1, const float* __restrict__ att_w2,
    const float* __restrict__ att_b2, const float* __restrict__ msg_w1,
    const float* __restrict__ msg_w2, const float* __restrict__ msg_b2,
    const float* __restrict__ out_w1, const float* __restrict__ out_b1,
    const float* __restrict__ out_w2, const float* __restrict__ out_b2,
    const float* __restrict__ ln_g, const float* __restrict__ ln_b,
    float* __restrict__ out, int Bn, int N, int nCopyBlocks)
{
    if ((int)blockIdx.x >= Bn) {
        // fused passthrough: out[Bn*32 ...] = adj  (float4, coalesced)
        int total4 = (Bn * N) >> 2;
        const float4* src = (const float4*)adj;
        float4* dst = (float4*)(out + (size_t)Bn * 32);
        int i = ((int)blockIdx.x - Bn) * 256 + (int)threadIdx.x;
        int stride = nCopyBlocks * 256;
        for (; i < total4; i += stride) dst[i] = src[i];
        return;
    }

    int row = blockIdx.x;                     // row = b*N + i
    int wave = threadIdx.x >> 6;
    int lane = threadIdx.x & 63;
    int hf = lane >> 5;
    int k = lane & 31;
    int b = row / N;

    float yi = yv[row * 32 + k];
    float Ai = Av[row * 32 + k];
    float yi0 = __shfl(yi, 0, 32);
    float w64 = att_w1[64 * 32 + k];          // adj coefficient row
    float w65 = att_w1[65 * 32 + k];          // edge_attr coefficient row
    float aw2 = att_w2[k];
    float ab2 = att_b2[0];
    float mw32 = msg_w1[32 * 32 + k];         // edge_attr row of msg_w1

    const float* adjrow = adj + (size_t)row * N;
    const float* ybase = yv + (size_t)b * N * 32;
    const float* Bbase = Bv + (size_t)b * N * 32;
    const float* bbase = basev + (size_t)b * N * 32;

    float macc = 0.0f;     // sum_j att * relu(msg hidden)   (lane k = dim k)
    float attsum = 0.0f;   // sum_j att

    int seg = N >> 2;                         // 192 columns per wave
    int jlo = wave * seg;
    int jhi = jlo + seg;
    for (int jb = jlo; jb < jhi; jb += 64) {
        float aval = (jb + lane < N) ? adjrow[jb + lane] : 0.0f;
        unsigned long long mask = __ballot(aval != 0.0f);
        while (mask) {
            int j0 = __ffsll((unsigned long long)mask) - 1; mask &= mask - 1;
            int j1 = -1;
            if (mask) { j1 = __ffsll((unsigned long long)mask) - 1; mask &= mask - 1; }
            int myj = hf ? j1 : j0;
            if (myj >= 0) {
                int j = jb + myj;
                float a = __shfl(aval, myj, 64);
                float yj = ybase[(size_t)j * 32 + k];
                float Bj = Bbase[(size_t)j * 32 + k];
                float bj = bbase[(size_t)j * 32 + k];
                // edge_attr = arccosh(max(-l_inner(y_i, y_j), 1+eps))
                float v = (k == 0) ? yi * yj : -yi * yj;
                float z = red32(v);
                z = fmaxf(z, 1.0f + EPSF);
                float e = facosh(z);
                // att hidden -> silu -> att_w2 dot -> sigmoid
                float hA = Ai + Bj + a * w64 + e * w65;
                float sl = hA * fsigm(hA);    // silu
                float s = red32(sl * aw2) + ab2;
                float att = fsigm(s) * a;
                // msg hidden -> relu, weighted accumulate
                float m = fmaf(e, mw32, bj);
                macc = fmaf(att, fmaxf(m, 0.0f), macc);
                attsum += att;
            }
        }
    }

    // combine the two 32-lane halves, then the 4 waves via LDS
    macc += __shfl_xor(macc, 32);
    attsum += __shfl_xor(attsum, 32);

    __shared__ float lmacc[4][32];
    __shared__ float latt[4];
    if (lane < 32) lmacc[wave][k] = macc;
    if (lane == 0) latt[wave] = attsum;
    __syncthreads();
    if (wave != 0) return;                    // no syncs after this point

    float sm = lmacc[0][k] + lmacc[1][k] + lmacc[2][k] + lmacc[3][k];
    float sa = latt[0] + latt[1] + latt[2] + latt[3];

    // msg = sm @ msg_w2 + sa * msg_b2   (linearity of W2 over the j-sum)
    float msg = sa * msg_b2[k];
    #pragma unroll 8
    for (int d0 = 0; d0 < 32; ++d0) {
        float v = __shfl(sm, d0, 32);
        msg = fmaf(v, msg_w2[d0 * 32 + k], msg);
    }

    // out MLP: relu(msg @ out_w1 + b1) @ out_w2 + b2
    float t = out_b1[k];
    #pragma unroll 8
    for (int d0 = 0; d0 < 32; ++d0) {
        float v = __shfl(msg, d0, 32);
        t = fmaf(v, out_w1[d0 * 32 + k], t);
    }
    t = fmaxf(t, 0.0f);
    float m2 = out_b2[k];
    #pragma unroll 8
    for (int d0 = 0; d0 < 32; ++d0) {
        float v = __shfl(t, d0, 32);
        m2 = fmaf(v, out_w2[d0 * 32 + k], m2);
    }

    // msg3 = transp0(y, proj_tan0(m2))
    float pm = (k == 0) ? 0.0f : m2;
    float lin = red32((k == 0) ? 0.0f : yi * pm);
    float coef = lin / (1.0f + yi0);
    float msg3 = pm + coef * ((k == 0) ? (yi0 + 1.0f) : yi);

    // h2 = expmap(y, msg3)
    float li = red32((k == 0) ? -msg3 * msg3 : msg3 * msg3);
    float un = sqrtf(fmaxf(li, EPSF));
    float2 sc = fsinhcosh(un);
    float h2 = sc.y * yi + (sc.x / un) * msg3;

    // u2 = logmap0(h2)
    float h20 = __shfl(h2, 0, 32);
    float dd = facosh(fmaxf(h20, 1.0f + EPSF));
    float sp = sqrtf(fmaxf(h20 * h20 - 1.0f, EPSF));
    float u2 = (k == 0) ? 0.0f : (dd / sp) * h2;

    // layernorm over components 1..31
    float mu = red32(u2) * (1.0f / 31.0f);            // u2[k=0] is 0
    float dv = (k == 0) ? 0.0f : (u2 - mu);
    float var = red32(dv * dv) * (1.0f / 31.0f);
    float inv = 1.0f / sqrtf(var + 1e-5f);
    float spk = (k == 0) ? 0.0f : fmaf(dv * inv, ln_g[k - 1], ln_b[k - 1]);

    // h2 = expmap0([u2_0, sp])   (component 0 ignored by expmap0)
    float nn2 = red32(spk * spk);
    float n2 = sqrtf(fmaxf(nn2, EPSF));
    float2 sc2 = fsinhcosh(n2);
    float h2b = (k == 0) ? sc2.y : (sc2.x / n2) * spk;

    // out = expmap0(proj_tan0(relu(logmap0(h2))))
    float hb0 = __shfl(h2b, 0, 32);
    float ddb = facosh(fmaxf(hb0, 1.0f + EPSF));
    float spb = sqrtf(fmaxf(hb0 * hb0 - 1.0f, EPSF));
    float r = (k == 0) ? 0.0f : fmaxf((ddb / spb) * h2b, 0.0f);
    float nn3 = red32(r * r);
    float n3 = sqrtf(fmaxf(nn3, EPSF));
    float2 sc3 = fsinhcosh(n3);
    float o = (k == 0) ? sc3.y : (sc3.x / n3) * r;

    if (lane < 32) out[row * 32 + k] = o;
}

extern "C" void kernel_launch(void* const* d_in, const int* in_sizes, int n_in,
                              void* d_out, int out_size, void* d_ws, size_t ws_size,
                              hipStream_t stream) {
    const float* x      = (const float*)d_in[0];
    const float* adj    = (const float*)d_in[1];
    const float* W_lin  = (const float*)d_in[2];
    const float* b_lin  = (const float*)d_in[3];
    const float* att_w1 = (const float*)d_in[4];
    const float* att_b1 = (const float*)d_in[5];
    const float* att_w2 = (const float*)d_in[6];
    const float* att_b2 = (const float*)d_in[7];
    const float* msg_w1 = (const float*)d_in[8];
    const float* msg_b1 = (const float*)d_in[9];
    const float* msg_w2 = (const float*)d_in[10];
    const float* msg_b2 = (const float*)d_in[11];
    const float* out_w1 = (const float*)d_in[12];
    const float* out_b1 = (const float*)d_in[13];
    const float* out_w2 = (const float*)d_in[14];
    const float* out_b2 = (const float*)d_in[15];
    const float* ln_g   = (const float*)d_in[16];
    const float* ln_b   = (const float*)d_in[17];

    float* out = (float*)d_out;

    const int D = 32;
    const int BN = in_sizes[0] / D;      // b*n = 1536
    const int N = in_sizes[1] / BN;      // 768

    float* yv    = (float*)d_ws;
    float* Av    = yv + (size_t)BN * D;
    float* Bv    = Av + (size_t)BN * D;
    float* basev = Bv + (size_t)BN * D;

    int blocks1 = (BN + 3) / 4;
    hipLaunchKernelGGL(hgcn_phase1, dim3(blocks1), dim3(256), 0, stream,
                       x, W_lin, b_lin, att_w1, att_b1, msg_w1, msg_b1,
                       yv, Av, Bv, basev, BN);

    int total4 = (BN * N) / 4;                       // adj element count / 4
    int nCopyBlocks = (total4 + 255) / 256;          // 1 float4 per thread
    hipLaunchKernelGGL(hgcn_phase2, dim3(BN + nCopyBlocks), dim3(256), 0, stream,
                       adj, yv, Av, Bv, basev,
                       att_w1, att_w2, att_b2, msg_w1, msg_w2, msg_b2,
                       out_w1, out_b1, out_w2, out_b2, ln_g, ln_b,
                       out, BN, N, nCopyBlocks);
}

// Round 13
// 118.332 us; speedup vs baseline: 1.3835x; 1.0023x over previous
//
#include <hip/hip_runtime.h>
#include <hip/hip_bf16.h>

#define EPSF 1e-6f

// 32-lane butterfly reduction (xor masks <32 stay within each 32-lane half of a wave64)
__device__ __forceinline__ float red32(float v) {
    v += __shfl_xor(v, 16);
    v += __shfl_xor(v, 8);
    v += __shfl_xor(v, 4);
    v += __shfl_xor(v, 2);
    v += __shfl_xor(v, 1);
    return v;
}

// paired reduction: two independent 32-lane butterflies, explicitly interleaved for ILP
__device__ __forceinline__ void red32x2(float& a, float& b) {
    float ta, tb;
    ta = __shfl_xor(a, 16); tb = __shfl_xor(b, 16); a += ta; b += tb;
    ta = __shfl_xor(a, 8);  tb = __shfl_xor(b, 8);  a += ta; b += tb;
    ta = __shfl_xor(a, 4);  tb = __shfl_xor(b, 4);  a += ta; b += tb;
    ta = __shfl_xor(a, 2);  tb = __shfl_xor(b, 2);  a += ta; b += tb;
    ta = __shfl_xor(a, 1);  tb = __shfl_xor(b, 1);  a += ta; b += tb;
}

// fast native transcendentals (v_exp_f32 / v_log_f32 / v_rcp_f32)
__device__ __forceinline__ float frcp(float x) { return __builtin_amdgcn_rcpf(x); }
__device__ __forceinline__ float fsigm(float x) { return frcp(1.0f + __expf(-x)); }
// valid for z >= 1+eps (our callers clamp first)
__device__ __forceinline__ float facosh(float z) {
    return __logf(z + sqrtf(fmaxf(z * z - 1.0f, 0.0f)));
}
__device__ __forceinline__ float2 fsinhcosh(float x) {
    float e = __expf(x);
    float ei = frcp(e);
    return make_float2(0.5f * (e - ei), 0.5f * (e + ei));  // (sinh, cosh)
}

// ---------------------------------------------------------------------------
// Phase 1: per-node precompute. One wave per node; lane k (mod 32) = dim k.
//   yv     = hyperboloid point after linear+bias chain
//   Av     = u @ att_w1[0:32,:]  + att_b1
//   Bv     = u @ att_w1[32:64,:]
//   basev  = u @ msg_w1[0:32,:]  + msg_b1
// ---------------------------------------------------------------------------
__global__ __launch_bounds__(256) void hgcn_phase1(
    const float* __restrict__ x, const float* __restrict__ W_lin,
    const float* __restrict__ b_lin, const float* __restrict__ att_w1,
    const float* __restrict__ att_b1, const float* __restrict__ msg_w1,
    const float* __restrict__ msg_b1,
    float* __restrict__ yv, float* __restrict__ Av,
    float* __restrict__ Bv, float* __restrict__ basev, int n_nodes)
{
    int wave = threadIdx.x >> 6;
    int node = blockIdx.x * 4 + wave;
    if (node >= n_nodes) return;
    int lane = threadIdx.x & 63;
    int k = lane & 31;

    float xk = x[node * 32 + k];
    // u = logmap0(x)
    float x0 = __shfl(xk, 0, 32);
    float dd = facosh(fmaxf(x0, 1.0f + EPSF));
    float sp = sqrtf(fmaxf(x0 * x0 - 1.0f, EPSF));
    float u = (k == 0) ? 0.0f : (dd / sp) * xk;

    // h = proj_tan0(u @ W_lin)
    float h = 0.0f;
    #pragma unroll 8
    for (int d0 = 0; d0 < 32; ++d0) {
        float ud = __shfl(u, d0, 32);
        h = fmaf(ud, W_lin[d0 * 32 + k], h);
    }
    if (k == 0) h = 0.0f;

    // y = expmap0(h)
    float nn = red32(h * h);
    float n = sqrtf(fmaxf(nn, EPSF));
    float2 sc = fsinhcosh(n);
    float y = (k == 0) ? sc.y : (sc.x / n) * h;

    // bias = transp0(y, proj_tan0(b_lin))
    float pb = (k == 0) ? 0.0f : b_lin[k];
    float y0 = __shfl(y, 0, 32);
    float lin = red32((k == 0) ? 0.0f : y * pb);
    float coef = lin / (1.0f + y0);
    float bias = pb + coef * ((k == 0) ? (y0 + 1.0f) : y);

    // y = expmap(y, bias)
    float li = red32((k == 0) ? -bias * bias : bias * bias);
    float un = sqrtf(fmaxf(li, EPSF));
    float2 sc2 = fsinhcosh(un);
    float y2 = sc2.y * y + (sc2.x / un) * bias;

    // u2 = logmap0(y)
    float y20 = __shfl(y2, 0, 32);
    float dd2 = facosh(fmaxf(y20, 1.0f + EPSF));
    float sp2 = sqrtf(fmaxf(y20 * y20 - 1.0f, EPSF));
    float u2 = (k == 0) ? 0.0f : (dd2 / sp2) * y2;

    // per-node projections
    float A = att_b1[k];
    float B = 0.0f;
    float bs = msg_b1[k];
    #pragma unroll 8
    for (int d0 = 0; d0 < 32; ++d0) {
        float ud = __shfl(u2, d0, 32);
        A = fmaf(ud, att_w1[d0 * 32 + k], A);
        B = fmaf(ud, att_w1[(32 + d0) * 32 + k], B);
        bs = fmaf(ud, msg_w1[d0 * 32 + k], bs);
    }

    if (lane < 32) {
        yv[node * 32 + k] = y2;
        Av[node * 32 + k] = A;
        Bv[node * 32 + k] = B;
        basev[node * 32 + k] = bs;
    }
}

// ---------------------------------------------------------------------------
// Phase 2: one BLOCK per output row (4 waves split the 768-column adj scan,
// 192 columns each). Each wave ballots its chunks and processes FOUR active
// edges/iter (two per 32-lane half, dummy-padded so all control flow stays
// wave-uniform; invalid edges are zeroed via flags). The two chains per half
// are register-independent -> the compiler interleaves the bpermute/exp
// dependency chains (2x ILP on the latency-bound path).
// Each block also copies its adj row to out (tuple output 2) as a 192xfloat4
// coalesced slice, issued before the scan so it overlaps compute.
// Partial sums combine through LDS; wave 0 runs the epilogue.
// ---------------------------------------------------------------------------
__global__ __launch_bounds__(256) void hgcn_phase2(
    const float* __restrict__ adj,
    const float* __restrict__ yv, const float* __restrict__ Av,
    const float* __restrict__ Bv, const float* __restrict__ basev,
    const float* __restrict__ att_w1, const float* __restrict__ att_w2,
    const float* __restrict__ att_b2, const float* __restrict__ msg_w1,
    const float* __restrict__ msg_w2, const float* __restrict__ msg_b2,
    const float* __restrict__ out_w1, const float* __restrict__ out_b1,
    const float* __restrict__ out_w2, const float* __restrict__ out_b2,
    const float* __restrict__ ln_g, const float* __restrict__ ln_b,
    float* __restrict__ out, int Bn, int N)
{
    int row = blockIdx.x;                     // row = b*N + i
    int wave = threadIdx.x >> 6;
    int lane = threadIdx.x & 63;
    int hf = lane >> 5;
    int k = lane & 31;
    int b = row / N;

    const float* adjrow = adj + (size_t)row * N;

    // fused passthrough: copy this row's adj slice to out[Bn*32 + row*N ...]
    {
        const float4* src4 = (const float4*)adjrow;
        float4* dst4 = (float4*)(out + (size_t)Bn * 32 + (size_t)row * N);
        for (int t = threadIdx.x; t < (N >> 2); t += blockDim.x)
            dst4[t] = src4[t];
    }

    float yi = yv[row * 32 + k];
    float Ai = Av[row * 32 + k];
    float yi0 = __shfl(yi, 0, 32);
    float w64 = att_w1[64 * 32 + k];          // adj coefficient row
    float w65 = att_w1[65 * 32 + k];          // edge_attr coefficient row
    float aw2 = att_w2[k];
    float ab2 = att_b2[0];
    float mw32 = msg_w1[32 * 32 + k];         // edge_attr row of msg_w1

    const float* ybase = yv + (size_t)b * N * 32;
    const float* Bbase = Bv + (size_t)b * N * 32;
    const float* bbase = basev + (size_t)b * N * 32;

    float macc = 0.0f;     // sum_j att * relu(msg hidden)   (lane k = dim k)
    float attsum = 0.0f;   // sum_j att

    int seg = N >> 2;                         // 192 columns per wave
    int jlo = wave * seg;
    int jhi = jlo + seg;
    for (int jc = jlo; jc < jhi; jc += 64) {
        float aval = (jc + lane < N) ? adjrow[jc + lane] : 0.0f;
        unsigned long long mask = __ballot(aval != 0.0f);
        while (mask) {
            // pop up to 4 edges; halves take {p0,p2} and {p1,p3}
            int p0 = __ffsll((unsigned long long)mask) - 1; mask &= mask - 1;
            int p1 = -1, p2 = -1, p3 = -1;
            if (mask) { p1 = __ffsll((unsigned long long)mask) - 1; mask &= mask - 1; }
            if (mask) { p2 = __ffsll((unsigned long long)mask) - 1; mask &= mask - 1; }
            if (mask) { p3 = __ffsll((unsigned long long)mask) - 1; mask &= mask - 1; }
            int pA = hf ? p1 : p0;
            int pB = hf ? p3 : p2;
            bool vA = pA >= 0;
            bool vB = pB >= 0;
            int iA = vA ? pA : 0;             // dummy lane 0 when invalid
            int iB = vB ? pB : 0;
            float aA = __shfl(aval, iA, 64);
            float aB = __shfl(aval, iB, 64);
            int jA = jc + iA;
            int jB = jc + iB;
            // gather both edges' per-node vectors (independent loads, mem ILP)
            float yjA = ybase[(size_t)jA * 32 + k];
            float yjB = ybase[(size_t)jB * 32 + k];
            float BjA = Bbase[(size_t)jA * 32 + k];
            float BjB = Bbase[(size_t)jB * 32 + k];
            float bjA = bbase[(size_t)jA * 32 + k];
            float bjB = bbase[(size_t)jB * 32 + k];
            // edge_attr = arccosh(max(-l_inner(y_i, y_j), 1+eps)) -- paired
            float zA = (k == 0) ? yi * yjA : -yi * yjA;
            float zB = (k == 0) ? yi * yjB : -yi * yjB;
            red32x2(zA, zB);
            float eA = facosh(fmaxf(zA, 1.0f + EPSF));
            float eB = facosh(fmaxf(zB, 1.0f + EPSF));
            // att hidden -> silu -> att_w2 dot -> sigmoid -- paired
            float hA = Ai + BjA + aA * w64 + eA * w65;
            float hB = Ai + BjB + aB * w64 + eB * w65;
            float slA = (hA * fsigm(hA)) * aw2;
            float slB = (hB * fsigm(hB)) * aw2;
            red32x2(slA, slB);
            float attA = vA ? fsigm(slA + ab2) * aA : 0.0f;
            float attB = vB ? fsigm(slB + ab2) * aB : 0.0f;
            // msg hidden -> relu, weighted accumulate
            float mA = fmaf(eA, mw32, bjA);
            float mB = fmaf(eB, mw32, bjB);
            macc = fmaf(attA, fmaxf(mA, 0.0f), macc);
            macc = fmaf(attB, fmaxf(mB, 0.0f), macc);
            attsum += attA + attB;
        }
    }

    // combine the two 32-lane halves, then the 4 waves via LDS
    macc += __shfl_xor(macc, 32);
    attsum += __shfl_xor(attsum, 32);

    __shared__ float lmacc[4][32];
    __shared__ float latt[4];
    if (lane < 32) lmacc[wave][k] = macc;
    if (lane == 0) latt[wave] = attsum;
    __syncthreads();
    if (wave != 0) return;                    // no syncs after this point

    float sm = lmacc[0][k] + lmacc[1][k] + lmacc[2][k] + lmacc[3][k];
    float sa = latt[0] + latt[1] + latt[2] + latt[3];

    // msg = sm @ msg_w2 + sa * msg_b2   (linearity of W2 over the j-sum)
    float msg = sa * msg_b2[k];
    #pragma unroll 8
    for (int d0 = 0; d0 < 32; ++d0) {
        float v = __shfl(sm, d0, 32);
        msg = fmaf(v, msg_w2[d0 * 32 + k], msg);
    }

    // out MLP: relu(msg @ out_w1 + b1) @ out_w2 + b2
    float t = out_b1[k];
    #pragma unroll 8
    for (int d0 = 0; d0 < 32; ++d0) {
        float v = __shfl(msg, d0, 32);
        t = fmaf(v, out_w1[d0 * 32 + k], t);
    }
    t = fmaxf(t, 0.0f);
    float m2 = out_b2[k];
    #pragma unroll 8
    for (int d0 = 0; d0 < 32; ++d0) {
        float v = __shfl(t, d0, 32);
        m2 = fmaf(v, out_w2[d0 * 32 + k], m2);
    }

    // msg3 = transp0(y, proj_tan0(m2))
    float pm = (k == 0) ? 0.0f : m2;
    float lin = red32((k == 0) ? 0.0f : yi * pm);
    float coef = lin / (1.0f + yi0);
    float msg3 = pm + coef * ((k == 0) ? (yi0 + 1.0f) : yi);

    // h2 = expmap(y, msg3)
    float li = red32((k == 0) ? -msg3 * msg3 : msg3 * msg3);
    float un = sqrtf(fmaxf(li, EPSF));
    float2 sc = fsinhcosh(un);
    float h2 = sc.y * yi + (sc.x / un) * msg3;

    // u2 = logmap0(h2)
    float h20 = __shfl(h2, 0, 32);
    float dd = facosh(fmaxf(h20, 1.0f + EPSF));
    float sp = sqrtf(fmaxf(h20 * h20 - 1.0f, EPSF));
    float u2 = (k == 0) ? 0.0f : (dd / sp) * h2;

    // layernorm over components 1..31
    float mu = red32(u2) * (1.0f / 31.0f);            // u2[k=0] is 0
    float dv = (k == 0) ? 0.0f : (u2 - mu);
    float var = red32(dv * dv) * (1.0f / 31.0f);
    float inv = 1.0f / sqrtf(var + 1e-5f);
    float spk = (k == 0) ? 0.0f : fmaf(dv * inv, ln_g[k - 1], ln_b[k - 1]);

    // h2 = expmap0([u2_0, sp])   (component 0 ignored by expmap0)
    float nn2 = red32(spk * spk);
    float n2 = sqrtf(fmaxf(nn2, EPSF));
    float2 sc2 = fsinhcosh(n2);
    float h2b = (k == 0) ? sc2.y : (sc2.x / n2) * spk;

    // out = expmap0(proj_tan0(relu(logmap0(h2))))
    float hb0 = __shfl(h2b, 0, 32);
    float ddb = facosh(fmaxf(hb0, 1.0f + EPSF));
    float spb = sqrtf(fmaxf(hb0 * hb0 - 1.0f, EPSF));
    float r = (k == 0) ? 0.0f : fmaxf((ddb / spb) * h2b, 0.0f);
    float nn3 = red32(r * r);
    float n3 = sqrtf(fmaxf(nn3, EPSF));
    float2 sc3 = fsinhcosh(n3);
    float o = (k == 0) ? sc3.y : (sc3.x / n3) * r;

    if (lane < 32) out[row * 32 + k] = o;
}

extern "C" void kernel_launch(void* const* d_in, const int* in_sizes, int n_in,
                              void* d_out, int out_size, void* d_ws, size_t ws_size,
                              hipStream_t stream) {
    const float* x      = (const float*)d_in[0];
    const float* adj    = (const float*)d_in[1];
    const float* W_lin  = (const float*)d_in[2];
    const float* b_lin  = (const float*)d_in[3];
    const float* att_w1 = (const float*)d_in[4];
    const float* att_b1 = (const float*)d_in[5];
    const float* att_w2 = (const float*)d_in[6];
    const float* att_b2 = (const float*)d_in[7];
    const float* msg_w1 = (const float*)d_in[8];
    const float* msg_b1 = (const float*)d_in[9];
    const float* msg_w2 = (const float*)d_in[10];
    const float* msg_b2 = (const float*)d_in[11];
    const float* out_w1 = (const float*)d_in[12];
    const float* out_b1 = (const float*)d_in[13];
    const float* out_w2 = (const float*)d_in[14];
    const float* out_b2 = (const float*)d_in[15];
    const float* ln_g   = (const float*)d_in[16];
    const float* ln_b   = (const float*)d_in[17];

    float* out = (float*)d_out;

    const int D = 32;
    const int BN = in_sizes[0] / D;      // b*n = 1536
    const int N = in_sizes[1] / BN;      // 768

    float* yv    = (float*)d_ws;
    float* Av    = yv + (size_t)BN * D;
    float* Bv    = Av + (size_t)BN * D;
    float* basev = Bv + (size_t)BN * D;

    int blocks1 = (BN + 3) / 4;
    hipLaunchKernelGGL(hgcn_phase1, dim3(blocks1), dim3(256), 0, stream,
                       x, W_lin, b_lin, att_w1, att_b1, msg_w1, msg_b1,
                       yv, Av, Bv, basev, BN);

    hipLaunchKernelGGL(hgcn_phase2, dim3(BN), dim3(256), 0, stream,
                       adj, yv, Av, Bv, basev,
                       att_w1, att_w2, att_b2, msg_w1, msg_w2, msg_b2,
                       out_w1, out_b1, out_w2, out_b2, ln_g, ln_b,
                       out, BN, N);
}